// Round 10
// baseline (492.546 us; speedup 1.0000x reference)
//
#include <hip/hip_runtime.h>
#include <math.h>
#include <stdint.h>

// RealNVP fused, MFMA v6: v2's proven LDS structure, but 4 column-tiles per
// wave (64 px) so staging VALU, barrier drains, and LDS fragment reads
// amortize over 2x pixels. Biases read from global (v5-proven) -> LDS exactly
// 40960 B. __launch_bounds__(256,3): ~170 VGPR cap — R6/R7 showed forcing
// higher occupancy spills the activation working set to scratch.
// ws layout per stage (stride WSTRIDE):
//   [0,4096)      L1 K=16 A-frag pairs: pair p: frag(2p)|frag(2p+1), lane*16
//   [4096,36864)  L2 K=32 A-frags: (m*4+c)*1024 + lane*16
//   [36864,40960) L3 K=32 A-frags: c*1024 + lane*16 (rows 8..15 zero)
//   [40960,41472) b1 f32[128]; [41472,41984) b2 f32[128]; [41984,42048) b3[16]

#define HWPIX   9216
#define NPIX    294912
#define WSTRIDE 45056
#define NFRAG   45
#define L2OFF   4096
#define L3OFF   36864
#define B1OFF   40960
#define B2OFF   41472
#define B3OFF   41984
#define NT      4                    // column tiles per wave (64 px)

typedef float    f32x4 __attribute__((ext_vector_type(4)));
typedef _Float16 f16x4 __attribute__((ext_vector_type(4)));
typedef _Float16 f16x8 __attribute__((ext_vector_type(8)));
typedef uint32_t u32x4 __attribute__((ext_vector_type(4)));

// ---------------------------------------------------------------------------
__global__ __launch_bounds__(256)
void prep_frags(const float* __restrict__ W1, const float* __restrict__ b1,
                const float* __restrict__ W2, const float* __restrict__ b2,
                const float* __restrict__ W3, const float* __restrict__ b3,
                char* __restrict__ ws)
{
    int t = blockIdx.x * 256 + threadIdx.x;      // 8*45*64 = 23040 exactly
    if (t >= 8 * NFRAG * 64) return;
    const int lane  = t & 63;
    const int f     = (t >> 6) % NFRAG;
    const int stage = t / (NFRAG * 64);
    const int pl = lane & 15, g = lane >> 4;
    const int pat = stage & 3;
    char* base = ws + stage * WSTRIDE;

    if (f < 8) {                       // L1 K=16 frag m=f (x-channel k, fi-folded)
        const int m = f;
        _Float16* dst = (_Float16*)(base + (m >> 1) * 1024 + lane * 16 + (m & 1) * 8);
#pragma unroll
        for (int e = 0; e < 4; ++e) {
            const int k = 4 * g + e;
            float val = 0.f;
            if (k < 8) {
                int j = -1;
                if      (pat == 0) j = (k >= 4) ? (k - 4) : -1;  // fi={4,5,6,7}
                else if (pat == 1) j = (k < 4)  ? k        : -1; // fi={0,1,2,3}
                else if (pat == 2) j = (k & 1)  ? (k >> 1) : -1; // fi={1,3,5,7}
                else               j = (k & 1)  ? -1 : (k >> 1); // fi={0,2,4,6}
                if (j >= 0) val = W1[stage * 512 + (16 * m + pl) * 4 + j];
            }
            dst[e] = (_Float16)val;
        }
    } else if (f < 40) {               // L2 K=32 frag (m,c)
        const int idx = f - 8, m = idx >> 2, c = idx & 3;
        _Float16* dst = (_Float16*)(base + L2OFF + idx * 1024 + lane * 16);
#pragma unroll
        for (int e = 0; e < 8; ++e) {
            const int k32 = (e < 4) ? (4 * g + e) : (16 + 4 * g + (e - 4));
            dst[e] = (_Float16)W2[stage * 16384 + (16 * m + pl) * 128 + 32 * c + k32];
        }
    } else if (f < 44) {               // L3 K=32 frag c (rows 8..15 zero)
        const int c = f - 40;
        _Float16* dst = (_Float16*)(base + L3OFF + c * 1024 + lane * 16);
#pragma unroll
        for (int e = 0; e < 8; ++e) {
            const int k32 = (e < 4) ? (4 * g + e) : (16 + 4 * g + (e - 4));
            dst[e] = (pl < 8) ? (_Float16)W3[stage * 1024 + pl * 128 + 32 * c + k32]
                              : (_Float16)0.f;
        }
    } else {                           // biases (f32) - consumed from global
        float* d1 = (float*)(base + B1OFF);
        d1[2 * lane]     = b1[stage * 128 + 2 * lane];
        d1[2 * lane + 1] = b1[stage * 128 + 2 * lane + 1];
        float* d2 = (float*)(base + B2OFF);
        d2[2 * lane]     = b2[stage * 128 + 2 * lane];
        d2[2 * lane + 1] = b2[stage * 128 + 2 * lane + 1];
        if (lane < 16)
            ((float*)(base + B3OFF))[lane] = (lane < 8) ? b3[stage * 8 + lane] : 0.f;
    }
}

// ---------------------------------------------------------------------------
__device__ __forceinline__ void load_pair(const void* p, f16x4& a, f16x4& b) {
    f16x8 v = *(const f16x8*)p;                        // ds_read_b128
    a = __builtin_shufflevector(v, v, 0, 1, 2, 3);
    b = __builtin_shufflevector(v, v, 4, 5, 6, 7);
}

__device__ __forceinline__ f16x8 cat8(f16x4 a, f16x4 b) {
    return __builtin_shufflevector(a, b, 0, 1, 2, 3, 4, 5, 6, 7);
}

// pack two f32 -> f16 pairs (cvt_pkrtz returns __fp16 vec -> convert elementwise)
__device__ __forceinline__ f16x4 pack4(float a0, float a1, float a2, float a3) {
    auto lo = __builtin_amdgcn_cvt_pkrtz(a0, a1);      // __fp16 ext_vector(2)
    auto hi = __builtin_amdgcn_cvt_pkrtz(a2, a3);
    f16x4 h;
    h[0] = (_Float16)lo[0]; h[1] = (_Float16)lo[1];
    h[2] = (_Float16)hi[0]; h[3] = (_Float16)hi[1];
    return h;
}

// pack f32x4 -> f16x4 (RTZ) then leaky in packed f16: max(h, 0.01h)
__device__ __forceinline__ f16x4 leaky_cvt(f32x4 a) {
    f16x4 h  = pack4(a[0], a[1], a[2], a[3]);
    f16x4 hs = h * (_Float16)0.01f;                    // v_pk_mul_f16 x2
    return __builtin_elementwise_max(h, hs);           // v_pk_max_f16 x2
}

__device__ __forceinline__ float fast_tanh(float x) {
    float e = __expf(2.0f * x);                        // v_mul + v_exp_f32
    return 1.0f - 2.0f * __builtin_amdgcn_rcpf(e + 1.0f);
}

__global__ __launch_bounds__(256, 3)
void realnvp_mfma(const float* __restrict__ x_in,
                  const char* __restrict__ wfrag,
                  float* __restrict__ out)
{
    __shared__ __align__(16) char lds[40960];          // 40 KiB

    const int tid  = threadIdx.x;
    const int w    = tid >> 6;
    const int lane = tid & 63;
    const int pl = lane & 15, g = lane >> 4;

    const int blockpx = blockIdx.x * 256;              // 256 px/block (4 waves x 64)
    const int bb   = blockpx / HWPIX;                  // 9216 % 256 == 0
    const int rem0 = blockpx - bb * HWPIX + w * 64;
    const float* xb = x_in + (size_t)bb * 8 * HWPIX + rem0;

    float xv[NT][4];
    float logdet[NT] = {0.f, 0.f, 0.f, 0.f};
#pragma unroll
    for (int t = 0; t < NT; ++t)
#pragma unroll
        for (int e = 0; e < 4; ++e)
            xv[t][e] = (g < 2) ? xb[(size_t)(4 * g + e) * HWPIX + t * 16 + pl] : 0.f;

#pragma unroll 1
    for (int st = 0; st < 8; ++st) {
        __syncthreads();                               // prior-stage LDS reads done
        {
            const char* gsrc = wfrag + st * WSTRIDE + tid * 16;
            char*       ldst = lds + tid * 16;
#pragma unroll
            for (int it = 0; it < 10; ++it)            // 40960 B
                *(u32x4*)(ldst + it * 4096) = *(const u32x4*)(gsrc + it * 4096);
        }
        __syncthreads();

        const char* wb = wfrag + st * WSTRIDE;         // biases from global (L1-hot)

        // x B-fragments (f16); lanes g>=2 are don't-care (A cols k>=8 are zero)
        f16x4 xh[NT];
#pragma unroll
        for (int t = 0; t < NT; ++t)
            xh[t] = pack4(xv[t][0], xv[t][1], xv[t][2], xv[t][3]);

        // ---- L1 (K=16): h1 = leaky(W1pad @ x + b1), bias = C-init ----
        f16x4 h1[NT][8];
        {
            f16x4 w1f[8];
#pragma unroll
            for (int pr = 0; pr < 4; ++pr)
                load_pair(lds + pr * 1024 + lane * 16, w1f[2 * pr], w1f[2 * pr + 1]);
#pragma unroll
            for (int m = 0; m < 8; ++m) {
                f32x4 bv = *(const f32x4*)(wb + B1OFF + m * 64 + g * 16);
#pragma unroll
                for (int t = 0; t < NT; ++t) {
                    f32x4 acc = __builtin_amdgcn_mfma_f32_16x16x16f16(w1f[m], xh[t], bv, 0, 0, 0);
                    h1[t][m] = leaky_cvt(acc);
                }
            }
        }

        // ---- L2 (K=32 x4): h2 = leaky(W2 @ h1 + b2) ----
        f16x4 h2[NT][8];
#pragma unroll
        for (int m = 0; m < 8; ++m) {
            f16x8 wf[4];
#pragma unroll
            for (int c = 0; c < 4; ++c)
                wf[c] = *(const f16x8*)(lds + L2OFF + (m * 4 + c) * 1024 + lane * 16);
            f32x4 bv = *(const f32x4*)(wb + B2OFF + m * 64 + g * 16);
#pragma unroll
            for (int t = 0; t < NT; ++t) {
                f32x4 acc = bv;
#pragma unroll
                for (int c = 0; c < 4; ++c)
                    acc = __builtin_amdgcn_mfma_f32_16x16x32_f16(
                        wf[c], cat8(h1[t][2 * c], h1[t][2 * c + 1]), acc, 0, 0, 0);
                h2[t][m] = leaky_cvt(acc);
            }
        }

        // ---- L3 (K=32 x4) + coupling ----
        {
            f16x8 w3f[4];
#pragma unroll
            for (int c = 0; c < 4; ++c)
                w3f[c] = *(const f16x8*)(lds + L3OFF + c * 1024 + lane * 16);
            f32x4 bv3 = *(const f32x4*)(wb + B3OFF + g * 16);

            const int pat = st & 3;
#pragma unroll
            for (int t = 0; t < NT; ++t) {
                f32x4 acc = bv3;
#pragma unroll
                for (int c = 0; c < 4; ++c)
                    acc = __builtin_amdgcn_mfma_f32_16x16x32_f16(
                        w3f[c], cat8(h2[t][2 * c], h2[t][2 * c + 1]), acc, 0, 0, 0);

                // D rows: g0 -> st[0..3] (s-pre), g1 -> st[4..7] (t-pre)
                float sv[4], ov[4];
#pragma unroll
                for (int r = 0; r < 4; ++r) sv[r] = fast_tanh(acc[r]);
#pragma unroll
                for (int r = 0; r < 4; ++r)
                    ov[r] = __int_as_float(
                        __builtin_amdgcn_ds_swizzle(__float_as_int(sv[r]), 0x401F)); // lane^16

                if (g == 0) logdet[t] += sv[0] + sv[1] + sv[2] + sv[3];

                float xn[4];
#pragma unroll
                for (int e = 0; e < 4; ++e) xn[e] = xv[t][e];
                if (pat == 0) {            // ci={0,1,2,3} @ g0
#pragma unroll
                    for (int e = 0; e < 4; ++e)
                        if (g == 0) xn[e] = xv[t][e] * __expf(sv[e]) + ov[e];
                } else if (pat == 1) {     // ci={4,5,6,7} @ g1
#pragma unroll
                    for (int e = 0; e < 4; ++e)
                        if (g == 1) xn[e] = xv[t][e] * __expf(ov[e]) + sv[e];
                } else if (pat == 2) {     // ci={0,2,4,6}: even e
#pragma unroll
                    for (int e = 0; e < 4; e += 2) {
                        const int k0 = e >> 1, k1 = 2 + (e >> 1);
                        if (g == 0) xn[e] = xv[t][e] * __expf(sv[k0]) + ov[k0];
                        if (g == 1) xn[e] = xv[t][e] * __expf(ov[k1]) + sv[k1];
                    }
                } else {                   // ci={1,3,5,7}: odd e
#pragma unroll
                    for (int e = 1; e < 4; e += 2) {
                        const int k0 = e >> 1, k1 = 2 + (e >> 1);
                        if (g == 0) xn[e] = xv[t][e] * __expf(sv[k0]) + ov[k0];
                        if (g == 1) xn[e] = xv[t][e] * __expf(ov[k1]) + sv[k1];
                    }
                }
#pragma unroll
                for (int e = 0; e < 4; ++e) xv[t][e] = xn[e];
            }
        }
    }

    // ---- outputs: x (B,8,H,W) then log_det (B,1,H,W) ----
    float* outx = out + (size_t)bb * 8 * HWPIX + rem0;
#pragma unroll
    for (int t = 0; t < NT; ++t) {
        if (g < 2)
#pragma unroll
            for (int e = 0; e < 4; ++e)
                outx[(size_t)(4 * g + e) * HWPIX + t * 16 + pl] = xv[t][e];
        if (g == 0)
            out[(size_t)NPIX * 8 + (size_t)bb * HWPIX + rem0 + t * 16 + pl] = logdet[t];
    }
}

extern "C" void kernel_launch(void* const* d_in, const int* in_sizes, int n_in,
                              void* d_out, int out_size, void* d_ws, size_t ws_size,
                              hipStream_t stream)
{
    const float* x  = (const float*)d_in[0];
    const float* W1 = (const float*)d_in[1];
    const float* b1 = (const float*)d_in[2];
    const float* W2 = (const float*)d_in[3];
    const float* b2 = (const float*)d_in[4];
    const float* W3 = (const float*)d_in[5];
    const float* b3 = (const float*)d_in[6];
    float* out = (float*)d_out;
    char*  ws  = (char*)d_ws;

    hipLaunchKernelGGL(prep_frags, dim3(90), dim3(256), 0, stream,
                       W1, b1, W2, b2, W3, b3, ws);
    hipLaunchKernelGGL(realnvp_mfma, dim3(NPIX / 256), dim3(256), 0, stream,
                       x, ws, out);
}

// Round 11
// 185.832 us; speedup vs baseline: 2.6505x; 2.6505x over previous
//
#include <hip/hip_runtime.h>
#include <math.h>
#include <stdint.h>

// RealNVP fused, MFMA v7: v2's per-wave body (proven 118us/absmax 0.03125,
// ~68 VGPR) in 512-thread blocks. v3 failed ONLY because __launch_bounds__
// (512,6) capped VGPR at 85 -> spill; here the bound is (512) alone.
// - 8 waves x 32 px = 256 px/block: staging per px halved vs v2.
// - biases from global (v5-proven) -> LDS exactly 40960 B -> 3 blocks/CU
//   = 24 waves/CU = 6 waves/SIMD (2x v2's TLP for pipe interleave).
// ws layout per stage (stride WSTRIDE):
//   [0,4096)      L1 K=16 A-frag pairs: pair p: frag(2p)|frag(2p+1), lane*16
//   [4096,36864)  L2 K=32 A-frags: (m*4+c)*1024 + lane*16
//   [36864,40960) L3 K=32 A-frags: c*1024 + lane*16 (rows 8..15 zero)
//   [40960,41472) b1 f32[128]; [41472,41984) b2 f32[128]; [41984,42048) b3[16]

#define HWPIX   9216
#define NPIX    294912
#define WSTRIDE 45056
#define NFRAG   45
#define L2OFF   4096
#define L3OFF   36864
#define B1OFF   40960
#define B2OFF   41472
#define B3OFF   41984

typedef float    f32x4 __attribute__((ext_vector_type(4)));
typedef _Float16 f16x4 __attribute__((ext_vector_type(4)));
typedef _Float16 f16x8 __attribute__((ext_vector_type(8)));
typedef uint32_t u32x4 __attribute__((ext_vector_type(4)));

// ---------------------------------------------------------------------------
__global__ __launch_bounds__(256)
void prep_frags(const float* __restrict__ W1, const float* __restrict__ b1,
                const float* __restrict__ W2, const float* __restrict__ b2,
                const float* __restrict__ W3, const float* __restrict__ b3,
                char* __restrict__ ws)
{
    int t = blockIdx.x * 256 + threadIdx.x;      // 8*45*64 = 23040 exactly
    if (t >= 8 * NFRAG * 64) return;
    const int lane  = t & 63;
    const int f     = (t >> 6) % NFRAG;
    const int stage = t / (NFRAG * 64);
    const int pl = lane & 15, g = lane >> 4;
    const int pat = stage & 3;
    char* base = ws + stage * WSTRIDE;

    if (f < 8) {                       // L1 K=16 frag m=f (x-channel k, fi-folded)
        const int m = f;
        _Float16* dst = (_Float16*)(base + (m >> 1) * 1024 + lane * 16 + (m & 1) * 8);
#pragma unroll
        for (int e = 0; e < 4; ++e) {
            const int k = 4 * g + e;
            float val = 0.f;
            if (k < 8) {
                int j = -1;
                if      (pat == 0) j = (k >= 4) ? (k - 4) : -1;  // fi={4,5,6,7}
                else if (pat == 1) j = (k < 4)  ? k        : -1; // fi={0,1,2,3}
                else if (pat == 2) j = (k & 1)  ? (k >> 1) : -1; // fi={1,3,5,7}
                else               j = (k & 1)  ? -1 : (k >> 1); // fi={0,2,4,6}
                if (j >= 0) val = W1[stage * 512 + (16 * m + pl) * 4 + j];
            }
            dst[e] = (_Float16)val;
        }
    } else if (f < 40) {               // L2 K=32 frag (m,c)
        const int idx = f - 8, m = idx >> 2, c = idx & 3;
        _Float16* dst = (_Float16*)(base + L2OFF + idx * 1024 + lane * 16);
#pragma unroll
        for (int e = 0; e < 8; ++e) {
            const int k32 = (e < 4) ? (4 * g + e) : (16 + 4 * g + (e - 4));
            dst[e] = (_Float16)W2[stage * 16384 + (16 * m + pl) * 128 + 32 * c + k32];
        }
    } else if (f < 44) {               // L3 K=32 frag c (rows 8..15 zero)
        const int c = f - 40;
        _Float16* dst = (_Float16*)(base + L3OFF + c * 1024 + lane * 16);
#pragma unroll
        for (int e = 0; e < 8; ++e) {
            const int k32 = (e < 4) ? (4 * g + e) : (16 + 4 * g + (e - 4));
            dst[e] = (pl < 8) ? (_Float16)W3[stage * 1024 + pl * 128 + 32 * c + k32]
                              : (_Float16)0.f;
        }
    } else {                           // biases (f32) - consumed from global
        float* d1 = (float*)(base + B1OFF);
        d1[2 * lane]     = b1[stage * 128 + 2 * lane];
        d1[2 * lane + 1] = b1[stage * 128 + 2 * lane + 1];
        float* d2 = (float*)(base + B2OFF);
        d2[2 * lane]     = b2[stage * 128 + 2 * lane];
        d2[2 * lane + 1] = b2[stage * 128 + 2 * lane + 1];
        if (lane < 16)
            ((float*)(base + B3OFF))[lane] = (lane < 8) ? b3[stage * 8 + lane] : 0.f;
    }
}

// ---------------------------------------------------------------------------
__device__ __forceinline__ void load_pair(const void* p, f16x4& a, f16x4& b) {
    f16x8 v = *(const f16x8*)p;                        // ds_read_b128
    a = __builtin_shufflevector(v, v, 0, 1, 2, 3);
    b = __builtin_shufflevector(v, v, 4, 5, 6, 7);
}

__device__ __forceinline__ f16x8 cat8(f16x4 a, f16x4 b) {
    return __builtin_shufflevector(a, b, 0, 1, 2, 3, 4, 5, 6, 7);
}

// pack two f32 -> f16 pairs (cvt_pkrtz returns __fp16 vec -> convert elementwise)
__device__ __forceinline__ f16x4 pack4(float a0, float a1, float a2, float a3) {
    auto lo = __builtin_amdgcn_cvt_pkrtz(a0, a1);      // __fp16 ext_vector(2)
    auto hi = __builtin_amdgcn_cvt_pkrtz(a2, a3);
    f16x4 h;
    h[0] = (_Float16)lo[0]; h[1] = (_Float16)lo[1];
    h[2] = (_Float16)hi[0]; h[3] = (_Float16)hi[1];
    return h;
}

// pack f32x4 -> f16x4 (RTZ) then leaky in packed f16: max(h, 0.01h)
__device__ __forceinline__ f16x4 leaky_cvt(f32x4 a) {
    f16x4 h  = pack4(a[0], a[1], a[2], a[3]);
    f16x4 hs = h * (_Float16)0.01f;                    // v_pk_mul_f16 x2
    return __builtin_elementwise_max(h, hs);           // v_pk_max_f16 x2
}

__device__ __forceinline__ float fast_tanh(float x) {
    float e = __expf(2.0f * x);                        // v_mul + v_exp_f32
    return 1.0f - 2.0f * __builtin_amdgcn_rcpf(e + 1.0f);
}

__global__ __launch_bounds__(512)
void realnvp_mfma(const float* __restrict__ x_in,
                  const char* __restrict__ wfrag,
                  float* __restrict__ out)
{
    __shared__ __align__(16) char lds[40960];          // 40 KiB -> 3 blocks/CU

    const int tid  = threadIdx.x;
    const int w    = tid >> 6;                         // wave 0..7
    const int lane = tid & 63;
    const int pl = lane & 15, g = lane >> 4;

    const int blockpx = blockIdx.x * 256;              // 256 px/block (8 waves x 32)
    const int bb   = blockpx / HWPIX;                  // 9216 % 256 == 0
    const int rem0 = blockpx - bb * HWPIX + w * 32;
    const float* xb = x_in + (size_t)bb * 8 * HWPIX + rem0;

    float xv[2][4];
    float logdet[2] = {0.f, 0.f};
#pragma unroll
    for (int t = 0; t < 2; ++t)
#pragma unroll
        for (int e = 0; e < 4; ++e)
            xv[t][e] = (g < 2) ? xb[(size_t)(4 * g + e) * HWPIX + t * 16 + pl] : 0.f;

#pragma unroll 1
    for (int st = 0; st < 8; ++st) {
        __syncthreads();                               // prior-stage LDS reads done
        {
            const char* gsrc = wfrag + st * WSTRIDE + tid * 16;
            char*       ldst = lds + tid * 16;
#pragma unroll
            for (int it = 0; it < 5; ++it)             // 5 x 8192 = 40960 B
                *(u32x4*)(ldst + it * 8192) = *(const u32x4*)(gsrc + it * 8192);
        }
        __syncthreads();

        const char* wb = wfrag + st * WSTRIDE;         // biases from global (L1-hot)

        // x B-fragments (f16); lanes g>=2 are don't-care (A cols k>=8 are zero)
        f16x4 xh[2];
#pragma unroll
        for (int t = 0; t < 2; ++t)
            xh[t] = pack4(xv[t][0], xv[t][1], xv[t][2], xv[t][3]);

        // ---- L1 (K=16): h1 = leaky(W1pad @ x + b1), bias = C-init ----
        f16x4 h1[2][8];
        {
            f16x4 w1f[8];
#pragma unroll
            for (int pr = 0; pr < 4; ++pr)
                load_pair(lds + pr * 1024 + lane * 16, w1f[2 * pr], w1f[2 * pr + 1]);
#pragma unroll
            for (int m = 0; m < 8; ++m) {
                f32x4 bv = *(const f32x4*)(wb + B1OFF + m * 64 + g * 16);
#pragma unroll
                for (int t = 0; t < 2; ++t) {
                    f32x4 acc = __builtin_amdgcn_mfma_f32_16x16x16f16(w1f[m], xh[t], bv, 0, 0, 0);
                    h1[t][m] = leaky_cvt(acc);
                }
            }
        }

        // ---- L2 (K=32 x4): h2 = leaky(W2 @ h1 + b2) ----
        f16x4 h2[2][8];
#pragma unroll
        for (int m = 0; m < 8; ++m) {
            f16x8 wf[4];
#pragma unroll
            for (int c = 0; c < 4; ++c)
                wf[c] = *(const f16x8*)(lds + L2OFF + (m * 4 + c) * 1024 + lane * 16);
            f32x4 bv = *(const f32x4*)(wb + B2OFF + m * 64 + g * 16);
#pragma unroll
            for (int t = 0; t < 2; ++t) {
                f32x4 acc = bv;
#pragma unroll
                for (int c = 0; c < 4; ++c)
                    acc = __builtin_amdgcn_mfma_f32_16x16x32_f16(
                        wf[c], cat8(h1[t][2 * c], h1[t][2 * c + 1]), acc, 0, 0, 0);
                h2[t][m] = leaky_cvt(acc);
            }
        }

        // ---- L3 (K=32 x4) + coupling ----
        {
            f16x8 w3f[4];
#pragma unroll
            for (int c = 0; c < 4; ++c)
                w3f[c] = *(const f16x8*)(lds + L3OFF + c * 1024 + lane * 16);
            f32x4 bv3 = *(const f32x4*)(wb + B3OFF + g * 16);

            const int pat = st & 3;
#pragma unroll
            for (int t = 0; t < 2; ++t) {
                f32x4 acc = bv3;
#pragma unroll
                for (int c = 0; c < 4; ++c)
                    acc = __builtin_amdgcn_mfma_f32_16x16x32_f16(
                        w3f[c], cat8(h2[t][2 * c], h2[t][2 * c + 1]), acc, 0, 0, 0);

                // D rows: g0 -> st[0..3] (s-pre), g1 -> st[4..7] (t-pre)
                float sv[4], ov[4];
#pragma unroll
                for (int r = 0; r < 4; ++r) sv[r] = fast_tanh(acc[r]);
#pragma unroll
                for (int r = 0; r < 4; ++r)
                    ov[r] = __int_as_float(
                        __builtin_amdgcn_ds_swizzle(__float_as_int(sv[r]), 0x401F)); // lane^16

                if (g == 0) logdet[t] += sv[0] + sv[1] + sv[2] + sv[3];

                float xn[4];
#pragma unroll
                for (int e = 0; e < 4; ++e) xn[e] = xv[t][e];
                if (pat == 0) {            // ci={0,1,2,3} @ g0
#pragma unroll
                    for (int e = 0; e < 4; ++e)
                        if (g == 0) xn[e] = xv[t][e] * __expf(sv[e]) + ov[e];
                } else if (pat == 1) {     // ci={4,5,6,7} @ g1
#pragma unroll
                    for (int e = 0; e < 4; ++e)
                        if (g == 1) xn[e] = xv[t][e] * __expf(ov[e]) + sv[e];
                } else if (pat == 2) {     // ci={0,2,4,6}: even e
#pragma unroll
                    for (int e = 0; e < 4; e += 2) {
                        const int k0 = e >> 1, k1 = 2 + (e >> 1);
                        if (g == 0) xn[e] = xv[t][e] * __expf(sv[k0]) + ov[k0];
                        if (g == 1) xn[e] = xv[t][e] * __expf(ov[k1]) + sv[k1];
                    }
                } else {                   // ci={1,3,5,7}: odd e
#pragma unroll
                    for (int e = 1; e < 4; e += 2) {
                        const int k0 = e >> 1, k1 = 2 + (e >> 1);
                        if (g == 0) xn[e] = xv[t][e] * __expf(sv[k0]) + ov[k0];
                        if (g == 1) xn[e] = xv[t][e] * __expf(ov[k1]) + sv[k1];
                    }
                }
#pragma unroll
                for (int e = 0; e < 4; ++e) xv[t][e] = xn[e];
            }
        }
    }

    // ---- outputs: x (B,8,H,W) then log_det (B,1,H,W) ----
    float* outx = out + (size_t)bb * 8 * HWPIX + rem0;
#pragma unroll
    for (int t = 0; t < 2; ++t) {
        if (g < 2)
#pragma unroll
            for (int e = 0; e < 4; ++e)
                outx[(size_t)(4 * g + e) * HWPIX + t * 16 + pl] = xv[t][e];
        if (g == 0)
            out[(size_t)NPIX * 8 + (size_t)bb * HWPIX + rem0 + t * 16 + pl] = logdet[t];
    }
}

extern "C" void kernel_launch(void* const* d_in, const int* in_sizes, int n_in,
                              void* d_out, int out_size, void* d_ws, size_t ws_size,
                              hipStream_t stream)
{
    const float* x  = (const float*)d_in[0];
    const float* W1 = (const float*)d_in[1];
    const float* b1 = (const float*)d_in[2];
    const float* W2 = (const float*)d_in[3];
    const float* b2 = (const float*)d_in[4];
    const float* W3 = (const float*)d_in[5];
    const float* b3 = (const float*)d_in[6];
    float* out = (float*)d_out;
    char*  ws  = (char*)d_ws;

    hipLaunchKernelGGL(prep_frags, dim3(90), dim3(256), 0, stream,
                       W1, b1, W2, b2, W3, b3, ws);
    hipLaunchKernelGGL(realnvp_mfma, dim3(NPIX / 256), dim3(512), 0, stream,
                       x, ws, out);
}